// Round 1
// baseline (697.755 us; speedup 1.0000x reference)
//
#include <hip/hip_runtime.h>
#include <hip/hip_bf16.h>
#include <math.h>

#define HIDDEN 2048
#define INNER  1024
#define NE     64
#define TOPK   8
#define NTOK   512

typedef float f32x4 __attribute__((ext_vector_type(4)));
typedef short bf16x8 __attribute__((ext_vector_type(8)));   // 8 bf16 (4 VGPRs) per guide §3

__device__ __forceinline__ unsigned short f2b(float f) {
  union { float f; unsigned int u; } v; v.f = f;
  unsigned int r = (v.u + 0x7fffu + ((v.u >> 16) & 1u)) >> 16;  // RNE
  return (unsigned short)r;
}

// ---------------- x -> bf16 ----------------
__global__ void xconv_kernel(const float* __restrict__ x, unsigned short* __restrict__ xb) {
  int i = blockIdx.x * 256 + threadIdx.x;             // one float4 per thread
  float4 v = ((const float4*)x)[i];
  ushort4 o;
  o.x = f2b(v.x); o.y = f2b(v.y); o.z = f2b(v.z); o.w = f2b(v.w);
  ((ushort4*)xb)[i] = o;
}

// ---------------- gating: 1 wave per token ----------------
__global__ void gating_kernel(const float* __restrict__ x, const float* __restrict__ gw,
                              const float* __restrict__ gb, int* __restrict__ counts,
                              int* __restrict__ topk_e, float* __restrict__ topk_w) {
  int t = blockIdx.x;
  int lane = threadIdx.x;          // = expert id, 0..63
  const float4* xr = (const float4*)(x + (size_t)t * HIDDEN);
  const float4* wr = (const float4*)(gw + (size_t)lane * HIDDEN);
  float acc = gb[lane];
  #pragma unroll 8
  for (int k = 0; k < HIDDEN / 4; ++k) {
    float4 a = xr[k], b = wr[k];
    acc += a.x * b.x + a.y * b.y + a.z * b.z + a.w * b.w;
  }
  // softmax over the 64 lanes
  float m = acc;
  #pragma unroll
  for (int off = 32; off; off >>= 1) m = fmaxf(m, __shfl_xor(m, off));
  float p = __expf(acc - m);
  float s = p;
  #pragma unroll
  for (int off = 32; off; off >>= 1) s += __shfl_xor(s, off);
  p /= s;

  // top-8 by repeated argmax (ties -> lower index, matches lax.top_k)
  float myp = p;
  float selw[TOPK]; int sele[TOPK];
  #pragma unroll
  for (int k = 0; k < TOPK; ++k) {
    float v = myp; int ei = lane;
    #pragma unroll
    for (int off = 32; off; off >>= 1) {
      float v2 = __shfl_xor(v, off); int e2 = __shfl_xor(ei, off);
      if (v2 > v || (v2 == v && e2 < ei)) { v = v2; ei = e2; }
    }
    selw[k] = v; sele[k] = ei;
    if (lane == ei) myp = -1.0f;
  }
  float ssum = 0.f;
  #pragma unroll
  for (int k = 0; k < TOPK; ++k) ssum += selw[k];
  if (lane < TOPK) {
    topk_e[t * TOPK + lane] = sele[lane];
    topk_w[t * TOPK + lane] = selw[lane] / ssum;
    atomicAdd(&counts[sele[lane]], 1);
  }
}

// ---------------- prefix scan of counts ----------------
__global__ void scan_kernel(const int* __restrict__ counts, int* __restrict__ offsets,
                            int* __restrict__ cursors) {
  if (threadIdx.x == 0) {
    int s = 0;
    for (int e = 0; e < NE; ++e) { offsets[e] = s; s += counts[e]; }
  }
  if (threadIdx.x < NE) cursors[threadIdx.x] = 0;
}

// ---------------- scatter assignments into expert-sorted order ----------------
__global__ void scatter_kernel(const int* __restrict__ topk_e, const float* __restrict__ topk_w,
                               const int* __restrict__ offsets, int* __restrict__ cursors,
                               int* __restrict__ perm_tok, float* __restrict__ perm_wt) {
  int i = blockIdx.x * 256 + threadIdx.x;   // 0..4095
  int e = topk_e[i];
  int p = atomicAdd(&cursors[e], 1);
  int pos = offsets[e] + p;
  perm_tok[pos] = i >> 3;
  perm_wt[pos] = topk_w[i];
}

// ---------------- phase 1: h = x @ w1[e]^T, act = gelu(gate)*up ----------------
// grid: (8 inner chunks of 128, 64 experts), block 256 (4 waves, 2x2 of 64x64)
__global__ __launch_bounds__(256, 2) void phase1_kernel(
    const unsigned short* __restrict__ xb, const float* __restrict__ w1,
    const int* __restrict__ offsets, const int* __restrict__ counts,
    const int* __restrict__ perm_tok, unsigned short* __restrict__ act) {
  const int e = blockIdx.y, c = blockIdx.x;
  const int n_e = counts[e];
  if (n_e == 0) return;
  const int off = offsets[e];
  const int tid = threadIdx.x;
  const int lane = tid & 63, wave = tid >> 6;
  const int wm = (wave & 1) * 64, wn = (wave >> 1) * 64;

  const float* wg = w1 + (size_t)e * (2 * INNER) * HIDDEN + (size_t)(c * 128) * HIDDEN;
  const float* wu = wg + (size_t)INNER * HIDDEN;

  __shared__ uint4 sA[128 * 8];
  __shared__ uint4 sBg[128 * 8];
  __shared__ uint4 sBu[128 * 8];
  __shared__ int stok[128];

  for (int m0 = 0; m0 < n_e; m0 += 128) {
    __syncthreads();
    if (tid < 128) {
      int idx = m0 + tid;
      stok[tid] = perm_tok[off + (idx < n_e ? idx : 0)];
    }
    __syncthreads();

    f32x4 gacc[4][4], uacc[4][4];
    #pragma unroll
    for (int i = 0; i < 4; ++i)
      #pragma unroll
      for (int j = 0; j < 4; ++j) { gacc[i][j] = (f32x4)0.f; uacc[i][j] = (f32x4)0.f; }

    for (int k0 = 0; k0 < HIDDEN; k0 += 64) {
      // gather loads into regs first (max loads in flight)
      uint4 va[4];
      const int ar = tid >> 3, as = tid & 7;
      #pragma unroll
      for (int p = 0; p < 4; ++p) {
        int r = p * 32 + ar;
        va[p] = *((const uint4*)(xb + (size_t)stok[r] * HIDDEN + k0) + as);
      }
      float4 vg[8], vu[8];
      const int br = tid >> 4, bc = tid & 15;
      #pragma unroll
      for (int p = 0; p < 8; ++p) {
        int r = p * 16 + br;
        vg[p] = *((const float4*)(wg + (size_t)r * HIDDEN + k0) + bc);
        vu[p] = *((const float4*)(wu + (size_t)r * HIDDEN + k0) + bc);
      }
      __syncthreads();   // previous tile's MFMA reads done
      #pragma unroll
      for (int p = 0; p < 4; ++p) {
        int r = p * 32 + ar;
        sA[r * 8 + (as ^ (r & 7))] = va[p];     // XOR-swizzled 16B slots
      }
      unsigned int* sBg2 = (unsigned int*)sBg;
      unsigned int* sBu2 = (unsigned int*)sBu;
      #pragma unroll
      for (int p = 0; p < 8; ++p) {
        int r = p * 16 + br;
        int slot = bc >> 1, half = bc & 1;
        int base = (r * 8 + (slot ^ (r & 7))) * 4 + half * 2;
        sBg2[base]     = (unsigned)f2b(vg[p].x) | ((unsigned)f2b(vg[p].y) << 16);
        sBg2[base + 1] = (unsigned)f2b(vg[p].z) | ((unsigned)f2b(vg[p].w) << 16);
        sBu2[base]     = (unsigned)f2b(vu[p].x) | ((unsigned)f2b(vu[p].y) << 16);
        sBu2[base + 1] = (unsigned)f2b(vu[p].z) | ((unsigned)f2b(vu[p].w) << 16);
      }
      __syncthreads();
      #pragma unroll
      for (int ks = 0; ks < 2; ++ks) {
        bf16x8 af[4], gf[4], uf[4];
        const int u = ks * 4 + (lane >> 4);
        #pragma unroll
        for (int mi = 0; mi < 4; ++mi) {
          int r = wm + mi * 16 + (lane & 15);
          af[mi] = __builtin_bit_cast(bf16x8, sA[r * 8 + (u ^ (r & 7))]);
        }
        #pragma unroll
        for (int ni = 0; ni < 4; ++ni) {
          int r = wn + ni * 16 + (lane & 15);
          gf[ni] = __builtin_bit_cast(bf16x8, sBg[r * 8 + (u ^ (r & 7))]);
          uf[ni] = __builtin_bit_cast(bf16x8, sBu[r * 8 + (u ^ (r & 7))]);
        }
        #pragma unroll
        for (int mi = 0; mi < 4; ++mi)
          #pragma unroll
          for (int ni = 0; ni < 4; ++ni) {
            gacc[mi][ni] = __builtin_amdgcn_mfma_f32_16x16x32_bf16(af[mi], gf[ni], gacc[mi][ni], 0, 0, 0);
            uacc[mi][ni] = __builtin_amdgcn_mfma_f32_16x16x32_bf16(af[mi], uf[ni], uacc[mi][ni], 0, 0, 0);
          }
      }
    }
    // epilogue: act = gelu_tanh(gate) * up, bf16
    #pragma unroll
    for (int mi = 0; mi < 4; ++mi) {
      #pragma unroll
      for (int r4 = 0; r4 < 4; ++r4) {
        int m = m0 + wm + mi * 16 + (lane >> 4) * 4 + r4;
        if (m < n_e) {
          unsigned short* arow = act + (size_t)(off + m) * INNER + c * 128 + wn;
          #pragma unroll
          for (int ni = 0; ni < 4; ++ni) {
            float g = gacc[mi][ni][r4];
            float uu = uacc[mi][ni][r4];
            float ge = 0.5f * g * (1.0f + tanhf(0.7978845608028654f * (g + 0.044715f * g * g * g)));
            arow[ni * 16 + (lane & 15)] = f2b(ge * uu);
          }
        }
      }
    }
  }
}

// ---------------- phase 2: y = act @ w2[e]^T, out[tok] += wt * y ----------------
// grid: (16 out chunks of 128, 64 experts), block 256
__global__ __launch_bounds__(256, 2) void phase2_kernel(
    const unsigned short* __restrict__ act, const float* __restrict__ w2,
    const int* __restrict__ offsets, const int* __restrict__ counts,
    const int* __restrict__ perm_tok, const float* __restrict__ perm_wt,
    float* __restrict__ out) {
  const int e = blockIdx.y, c = blockIdx.x;
  const int n_e = counts[e];
  if (n_e == 0) return;
  const int off = offsets[e];
  const int tid = threadIdx.x;
  const int lane = tid & 63, wave = tid >> 6;
  const int wm = (wave & 1) * 64, wn = (wave >> 1) * 64;

  const float* wb = w2 + (size_t)e * HIDDEN * INNER + (size_t)(c * 128) * INNER;

  __shared__ uint4 sA[128 * 8];
  __shared__ uint4 sB[128 * 8];

  for (int m0 = 0; m0 < n_e; m0 += 128) {
    f32x4 acc[4][4];
    #pragma unroll
    for (int i = 0; i < 4; ++i)
      #pragma unroll
      for (int j = 0; j < 4; ++j) acc[i][j] = (f32x4)0.f;

    for (int k0 = 0; k0 < INNER; k0 += 64) {
      uint4 va[4];
      const int ar = tid >> 3, as = tid & 7;
      #pragma unroll
      for (int p = 0; p < 4; ++p) {
        int m = m0 + p * 32 + ar;
        int row = off + (m < n_e ? m : n_e - 1);
        va[p] = *((const uint4*)(act + (size_t)row * INNER + k0) + as);
      }
      float4 vb[8];
      const int br = tid >> 4, bc = tid & 15;
      #pragma unroll
      for (int p = 0; p < 8; ++p) {
        int r = p * 16 + br;
        vb[p] = *((const float4*)(wb + (size_t)r * INNER + k0) + bc);
      }
      __syncthreads();
      #pragma unroll
      for (int p = 0; p < 4; ++p) {
        int r = p * 32 + ar;
        sA[r * 8 + (as ^ (r & 7))] = va[p];
      }
      unsigned int* sB2 = (unsigned int*)sB;
      #pragma unroll
      for (int p = 0; p < 8; ++p) {
        int r = p * 16 + br;
        int slot = bc >> 1, half = bc & 1;
        int base = (r * 8 + (slot ^ (r & 7))) * 4 + half * 2;
        sB2[base]     = (unsigned)f2b(vb[p].x) | ((unsigned)f2b(vb[p].y) << 16);
        sB2[base + 1] = (unsigned)f2b(vb[p].z) | ((unsigned)f2b(vb[p].w) << 16);
      }
      __syncthreads();
      #pragma unroll
      for (int ks = 0; ks < 2; ++ks) {
        bf16x8 af[4], bf[4];
        const int u = ks * 4 + (lane >> 4);
        #pragma unroll
        for (int mi = 0; mi < 4; ++mi) {
          int r = wm + mi * 16 + (lane & 15);
          af[mi] = __builtin_bit_cast(bf16x8, sA[r * 8 + (u ^ (r & 7))]);
        }
        #pragma unroll
        for (int ni = 0; ni < 4; ++ni) {
          int r = wn + ni * 16 + (lane & 15);
          bf[ni] = __builtin_bit_cast(bf16x8, sB[r * 8 + (u ^ (r & 7))]);
        }
        #pragma unroll
        for (int mi = 0; mi < 4; ++mi)
          #pragma unroll
          for (int ni = 0; ni < 4; ++ni)
            acc[mi][ni] = __builtin_amdgcn_mfma_f32_16x16x32_bf16(af[mi], bf[ni], acc[mi][ni], 0, 0, 0);
      }
      __syncthreads();   // keep tiles stable until everyone is done before next overwrite
    }
    // epilogue: out[tok, c*128 + col] += wt * y
    #pragma unroll
    for (int mi = 0; mi < 4; ++mi) {
      #pragma unroll
      for (int r4 = 0; r4 < 4; ++r4) {
        int m = m0 + wm + mi * 16 + (lane >> 4) * 4 + r4;
        if (m < n_e) {
          int tok = perm_tok[off + m];
          float wt = perm_wt[off + m];
          float* orow = out + (size_t)tok * HIDDEN + c * 128 + wn;
          #pragma unroll
          for (int ni = 0; ni < 4; ++ni)
            atomicAdd(&orow[ni * 16 + (lane & 15)], wt * acc[mi][ni][r4]);
        }
      }
    }
  }
}

extern "C" void kernel_launch(void* const* d_in, const int* in_sizes, int n_in,
                              void* d_out, int out_size, void* d_ws, size_t ws_size,
                              hipStream_t stream) {
  const float* x  = (const float*)d_in[0];
  const float* gw = (const float*)d_in[1];
  const float* gb = (const float*)d_in[2];
  const float* w1 = (const float*)d_in[3];
  const float* w2 = (const float*)d_in[4];
  float* out = (float*)d_out;

  char* ws = (char*)d_ws;
  int*   counts   = (int*)(ws + 0x000);
  int*   offsets  = (int*)(ws + 0x100);
  int*   cursors  = (int*)(ws + 0x200);
  int*   topk_e   = (int*)(ws + 0x1000);
  float* topk_w   = (float*)(ws + 0x5000);
  int*   perm_tok = (int*)(ws + 0x9000);
  float* perm_wt  = (float*)(ws + 0xD000);
  unsigned short* xb  = (unsigned short*)(ws + 0x11000);   // 512*2048 bf16 = 2 MB
  unsigned short* act = (unsigned short*)(ws + 0x220000);  // 4096*1024 bf16 = 8 MB

  hipMemsetAsync(ws, 0, 0x400, stream);                              // counts/offsets/cursors
  hipMemsetAsync(d_out, 0, (size_t)out_size * sizeof(float), stream);

  xconv_kernel<<<(NTOK * HIDDEN / 4) / 256, 256, 0, stream>>>(x, xb);
  gating_kernel<<<NTOK, 64, 0, stream>>>(x, gw, gb, counts, topk_e, topk_w);
  scan_kernel<<<1, 64, 0, stream>>>(counts, offsets, cursors);
  scatter_kernel<<<(NTOK * TOPK) / 256, 256, 0, stream>>>(topk_e, topk_w, offsets, cursors,
                                                          perm_tok, perm_wt);
  phase1_kernel<<<dim3(8, NE), 256, 0, stream>>>(xb, w1, offsets, counts, perm_tok, act);
  phase2_kernel<<<dim3(16, NE), 256, 0, stream>>>(act, w2, offsets, counts, perm_tok, perm_wt, out);
}

// Round 2
// 565.630 us; speedup vs baseline: 1.2336x; 1.2336x over previous
//
#include <hip/hip_runtime.h>
#include <hip/hip_bf16.h>

#define HIDDEN 2048
#define INNER  1024
#define NE     64
#define TOPK   8
#define NTOK   512

typedef float f32x4 __attribute__((ext_vector_type(4)));
typedef short bf16x8 __attribute__((ext_vector_type(8)));

__device__ __forceinline__ unsigned short b16(float f) {
  return __builtin_bit_cast(unsigned short, __float2bfloat16(f));
}
__device__ __forceinline__ unsigned int pk2(float lo, float hi) {
  return (unsigned)b16(lo) | ((unsigned)b16(hi) << 16);
}

// ---------------- x -> bf16 ----------------
__global__ void xconv_kernel(const float* __restrict__ x, unsigned short* __restrict__ xb) {
  int i = blockIdx.x * 256 + threadIdx.x;
  float4 v = ((const float4*)x)[i];
  ushort4 o;
  o.x = b16(v.x); o.y = b16(v.y); o.z = b16(v.z); o.w = b16(v.w);
  ((ushort4*)xb)[i] = o;
}

// ---------------- gating: 4 waves per token (K-split), wave0 does softmax+topk ----------------
__global__ __launch_bounds__(256) void gating_kernel(const float* __restrict__ x, const float* __restrict__ gw,
                                                     const float* __restrict__ gb, int* __restrict__ counts,
                                                     int* __restrict__ topk_e, float* __restrict__ topk_w) {
  int t = blockIdx.x;
  int lane = threadIdx.x & 63, w = threadIdx.x >> 6;
  __shared__ float sP[4][NE];
  const float4* xr = (const float4*)(x + (size_t)t * HIDDEN + w * 512);
  const float4* wr = (const float4*)(gw + (size_t)lane * HIDDEN + w * 512);
  float acc = 0.f;
  #pragma unroll 8
  for (int k = 0; k < 128; ++k) {
    float4 a = xr[k], b = wr[k];
    acc += a.x * b.x + a.y * b.y + a.z * b.z + a.w * b.w;
  }
  sP[w][lane] = acc;
  __syncthreads();
  if (w == 0) {
    float logit = gb[lane] + sP[0][lane] + sP[1][lane] + sP[2][lane] + sP[3][lane];
    float m = logit;
    #pragma unroll
    for (int off = 32; off; off >>= 1) m = fmaxf(m, __shfl_xor(m, off));
    float p = __expf(logit - m);
    float s = p;
    #pragma unroll
    for (int off = 32; off; off >>= 1) s += __shfl_xor(s, off);
    p /= s;
    float myp = p;
    float selw[TOPK]; int sele[TOPK];
    #pragma unroll
    for (int k = 0; k < TOPK; ++k) {
      float v = myp; int ei = lane;
      #pragma unroll
      for (int off = 32; off; off >>= 1) {
        float v2 = __shfl_xor(v, off); int e2 = __shfl_xor(ei, off);
        if (v2 > v || (v2 == v && e2 < ei)) { v = v2; ei = e2; }
      }
      selw[k] = v; sele[k] = ei;
      if (lane == ei) myp = -1.0f;
    }
    float ss = 0.f;
    #pragma unroll
    for (int k = 0; k < TOPK; ++k) ss += selw[k];
    if (lane < TOPK) {
      topk_e[t * TOPK + lane] = sele[lane];
      topk_w[t * TOPK + lane] = selw[lane] / ss;
      atomicAdd(&counts[sele[lane]], 1);
    }
  }
}

// ---------------- parallel exclusive scan over 64 counts ----------------
__global__ void scan_kernel(const int* __restrict__ counts, int* __restrict__ offsets,
                            int* __restrict__ cursors) {
  int lane = threadIdx.x;
  int c = counts[lane];
  int s = c;
  #pragma unroll
  for (int off = 1; off < 64; off <<= 1) {
    int o = __shfl_up(s, off);
    if (lane >= off) s += o;
  }
  offsets[lane] = s - c;
  cursors[lane] = 0;
}

// ---------------- scatter assignments into expert-sorted order ----------------
__global__ void scatter_kernel(const int* __restrict__ topk_e, const float* __restrict__ topk_w,
                               const int* __restrict__ offsets, int* __restrict__ cursors,
                               int* __restrict__ perm_tok, float* __restrict__ perm_wt) {
  int i = blockIdx.x * 256 + threadIdx.x;
  int e = topk_e[i];
  int p = atomicAdd(&cursors[e], 1);
  int pos = offsets[e] + p;
  perm_tok[pos] = i >> 3;
  perm_wt[pos] = topk_w[i];
}

// ---------------- phase 1: h = x @ w1[e]^T, act = gelu(gate)*up ----------------
// tile 128(M) x 64(N), grid (16 inner chunks, 64 experts), 4 waves as 2Mx2N
__global__ __launch_bounds__(256, 2) void phase1_kernel(
    const unsigned short* __restrict__ xb, const float* __restrict__ w1,
    const int* __restrict__ offsets, const int* __restrict__ counts,
    const int* __restrict__ perm_tok, unsigned short* __restrict__ act) {
  const int e = blockIdx.y, c = blockIdx.x;
  const int n_e = counts[e];
  if (n_e == 0) return;
  const int off = offsets[e];
  const int tid = threadIdx.x;
  const int lane = tid & 63, wave = tid >> 6;
  const int wm = (wave & 1) * 64, wn = (wave >> 1) * 32;

  const float* wg = w1 + (size_t)e * (2 * INNER) * HIDDEN + (size_t)(c * 64) * HIDDEN;
  const float* wu = wg + (size_t)INNER * HIDDEN;

  __shared__ uint4 sA[128 * 8];   // 128 tokens x 64 bf16
  __shared__ uint4 sBg[64 * 8];   // 64 gate rows x 64 bf16
  __shared__ uint4 sBu[64 * 8];
  __shared__ int stok[128];

  for (int m0 = 0; m0 < n_e; m0 += 128) {
    __syncthreads();
    if (tid < 128) {
      int idx = m0 + tid;
      stok[tid] = perm_tok[off + (idx < n_e ? idx : 0)];
    }
    __syncthreads();

    f32x4 gacc[4][2], uacc[4][2];
    #pragma unroll
    for (int i = 0; i < 4; ++i)
      #pragma unroll
      for (int j = 0; j < 2; ++j) { gacc[i][j] = (f32x4)0.f; uacc[i][j] = (f32x4)0.f; }

    for (int k0 = 0; k0 < HIDDEN; k0 += 64) {
      uint4 va[4];
      const int ar = tid >> 3, as = tid & 7;
      #pragma unroll
      for (int p = 0; p < 4; ++p) {
        int r = p * 32 + ar;
        va[p] = *((const uint4*)(xb + (size_t)stok[r] * HIDDEN + k0) + as);
      }
      f32x4 vg[4], vu[4];
      const int br = tid >> 4, bc = tid & 15;
      #pragma unroll
      for (int p = 0; p < 4; ++p) {
        int r = p * 16 + br;
        vg[p] = __builtin_nontemporal_load((const f32x4*)(wg + (size_t)r * HIDDEN + k0) + bc);
        vu[p] = __builtin_nontemporal_load((const f32x4*)(wu + (size_t)r * HIDDEN + k0) + bc);
      }
      __syncthreads();   // previous tile's LDS reads complete
      #pragma unroll
      for (int p = 0; p < 4; ++p) {
        int r = p * 32 + ar;
        sA[r * 8 + (as ^ (r & 7))] = va[p];
      }
      uint2* g2 = (uint2*)sBg;
      uint2* u2 = (uint2*)sBu;
      #pragma unroll
      for (int p = 0; p < 4; ++p) {
        int r = p * 16 + br;
        int slot = bc >> 1, half = bc & 1;
        int bidx = (r * 8 + (slot ^ (r & 7))) * 2 + half;
        g2[bidx] = make_uint2(pk2(vg[p].x, vg[p].y), pk2(vg[p].z, vg[p].w));
        u2[bidx] = make_uint2(pk2(vu[p].x, vu[p].y), pk2(vu[p].z, vu[p].w));
      }
      __syncthreads();
      #pragma unroll
      for (int ks = 0; ks < 2; ++ks) {
        const int u = ks * 4 + (lane >> 4);
        bf16x8 af[4], gf[2], uf[2];
        #pragma unroll
        for (int mi = 0; mi < 4; ++mi) {
          int r = wm + mi * 16 + (lane & 15);
          af[mi] = __builtin_bit_cast(bf16x8, sA[r * 8 + (u ^ (r & 7))]);
        }
        #pragma unroll
        for (int ni = 0; ni < 2; ++ni) {
          int r = wn + ni * 16 + (lane & 15);
          gf[ni] = __builtin_bit_cast(bf16x8, sBg[r * 8 + (u ^ (r & 7))]);
          uf[ni] = __builtin_bit_cast(bf16x8, sBu[r * 8 + (u ^ (r & 7))]);
        }
        #pragma unroll
        for (int mi = 0; mi < 4; ++mi)
          #pragma unroll
          for (int ni = 0; ni < 2; ++ni) {
            gacc[mi][ni] = __builtin_amdgcn_mfma_f32_16x16x32_bf16(af[mi], gf[ni], gacc[mi][ni], 0, 0, 0);
            uacc[mi][ni] = __builtin_amdgcn_mfma_f32_16x16x32_bf16(af[mi], uf[ni], uacc[mi][ni], 0, 0, 0);
          }
      }
    }
    // epilogue: act = gelu_tanh(gate) * up  (sigmoid identity, one v_exp)
    #pragma unroll
    for (int mi = 0; mi < 4; ++mi) {
      #pragma unroll
      for (int r4 = 0; r4 < 4; ++r4) {
        int m = m0 + wm + mi * 16 + (lane >> 4) * 4 + r4;
        if (m < n_e) {
          unsigned short* arow = act + (size_t)(off + m) * INNER + c * 64 + wn;
          #pragma unroll
          for (int ni = 0; ni < 2; ++ni) {
            float g = gacc[mi][ni][r4];
            float uu = uacc[mi][ni][r4];
            float ge = g / (1.0f + __expf(-1.5957691216057308f * (g + 0.044715f * g * g * g)));
            arow[ni * 16 + (lane & 15)] = b16(ge * uu);
          }
        }
      }
    }
  }
}

// ---------------- phase 2: y = act @ w2[e]^T, out[tok] += wt * y ----------------
// tile 128(M) x 64(N out cols), grid (32 chunks, 64 experts)
__global__ __launch_bounds__(256, 2) void phase2_kernel(
    const unsigned short* __restrict__ act, const float* __restrict__ w2,
    const int* __restrict__ offsets, const int* __restrict__ counts,
    const int* __restrict__ perm_tok, const float* __restrict__ perm_wt,
    float* __restrict__ out) {
  const int e = blockIdx.y, c = blockIdx.x;
  const int n_e = counts[e];
  if (n_e == 0) return;
  const int off = offsets[e];
  const int tid = threadIdx.x;
  const int lane = tid & 63, wave = tid >> 6;
  const int wm = (wave & 1) * 64, wn = (wave >> 1) * 32;

  const float* wb = w2 + (size_t)e * HIDDEN * INNER + (size_t)(c * 64) * INNER;

  __shared__ uint4 sA[128 * 8];   // 128 act rows x 64 bf16
  __shared__ uint4 sB[64 * 8];    // 64 w2 rows x 64 bf16

  for (int m0 = 0; m0 < n_e; m0 += 128) {
    f32x4 acc[4][2];
    #pragma unroll
    for (int i = 0; i < 4; ++i)
      #pragma unroll
      for (int j = 0; j < 2; ++j) acc[i][j] = (f32x4)0.f;

    for (int k0 = 0; k0 < INNER; k0 += 64) {
      uint4 va[4];
      const int ar = tid >> 3, as = tid & 7;
      #pragma unroll
      for (int p = 0; p < 4; ++p) {
        int m = m0 + p * 32 + ar;
        int row = off + (m < n_e ? m : n_e - 1);
        va[p] = *((const uint4*)(act + (size_t)row * INNER + k0) + as);
      }
      f32x4 vb[4];
      const int br = tid >> 4, bc = tid & 15;
      #pragma unroll
      for (int p = 0; p < 4; ++p) {
        int r = p * 16 + br;
        vb[p] = __builtin_nontemporal_load((const f32x4*)(wb + (size_t)r * INNER + k0) + bc);
      }
      __syncthreads();   // previous tile's LDS reads complete
      #pragma unroll
      for (int p = 0; p < 4; ++p) {
        int r = p * 32 + ar;
        sA[r * 8 + (as ^ (r & 7))] = va[p];
      }
      uint2* b2 = (uint2*)sB;
      #pragma unroll
      for (int p = 0; p < 4; ++p) {
        int r = p * 16 + br;
        int slot = bc >> 1, half = bc & 1;
        int bidx = (r * 8 + (slot ^ (r & 7))) * 2 + half;
        b2[bidx] = make_uint2(pk2(vb[p].x, vb[p].y), pk2(vb[p].z, vb[p].w));
      }
      __syncthreads();
      #pragma unroll
      for (int ks = 0; ks < 2; ++ks) {
        const int u = ks * 4 + (lane >> 4);
        bf16x8 af[4], bfr[2];
        #pragma unroll
        for (int mi = 0; mi < 4; ++mi) {
          int r = wm + mi * 16 + (lane & 15);
          af[mi] = __builtin_bit_cast(bf16x8, sA[r * 8 + (u ^ (r & 7))]);
        }
        #pragma unroll
        for (int ni = 0; ni < 2; ++ni) {
          int r = wn + ni * 16 + (lane & 15);
          bfr[ni] = __builtin_bit_cast(bf16x8, sB[r * 8 + (u ^ (r & 7))]);
        }
        #pragma unroll
        for (int mi = 0; mi < 4; ++mi)
          #pragma unroll
          for (int ni = 0; ni < 2; ++ni)
            acc[mi][ni] = __builtin_amdgcn_mfma_f32_16x16x32_bf16(af[mi], bfr[ni], acc[mi][ni], 0, 0, 0);
      }
    }
    // epilogue: out[tok, c*64 + col] += wt * y
    #pragma unroll
    for (int mi = 0; mi < 4; ++mi) {
      #pragma unroll
      for (int r4 = 0; r4 < 4; ++r4) {
        int m = m0 + wm + mi * 16 + (lane >> 4) * 4 + r4;
        if (m < n_e) {
          int tok = perm_tok[off + m];
          float wt = perm_wt[off + m];
          float* orow = out + (size_t)tok * HIDDEN + c * 64 + wn;
          #pragma unroll
          for (int ni = 0; ni < 2; ++ni)
            atomicAdd(&orow[ni * 16 + (lane & 15)], wt * acc[mi][ni][r4]);
        }
      }
    }
  }
}

extern "C" void kernel_launch(void* const* d_in, const int* in_sizes, int n_in,
                              void* d_out, int out_size, void* d_ws, size_t ws_size,
                              hipStream_t stream) {
  const float* x  = (const float*)d_in[0];
  const float* gw = (const float*)d_in[1];
  const float* gb = (const float*)d_in[2];
  const float* w1 = (const float*)d_in[3];
  const float* w2 = (const float*)d_in[4];
  float* out = (float*)d_out;

  char* ws = (char*)d_ws;
  int*   counts   = (int*)(ws + 0x000);
  int*   offsets  = (int*)(ws + 0x100);
  int*   cursors  = (int*)(ws + 0x200);
  int*   topk_e   = (int*)(ws + 0x1000);
  float* topk_w   = (float*)(ws + 0x5000);
  int*   perm_tok = (int*)(ws + 0x9000);
  float* perm_wt  = (float*)(ws + 0xD000);
  unsigned short* xb  = (unsigned short*)(ws + 0x11000);   // 512*2048 bf16 = 2 MB
  unsigned short* act = (unsigned short*)(ws + 0x220000);  // 4096*1024 bf16 = 8 MB

  hipMemsetAsync(ws, 0, 0x400, stream);
  hipMemsetAsync(d_out, 0, (size_t)out_size * sizeof(float), stream);

  xconv_kernel<<<(NTOK * HIDDEN / 4) / 256, 256, 0, stream>>>(x, xb);
  gating_kernel<<<NTOK, 256, 0, stream>>>(x, gw, gb, counts, topk_e, topk_w);
  scan_kernel<<<1, 64, 0, stream>>>(counts, offsets, cursors);
  scatter_kernel<<<(NTOK * TOPK) / 256, 256, 0, stream>>>(topk_e, topk_w, offsets, cursors,
                                                          perm_tok, perm_wt);
  phase1_kernel<<<dim3(16, NE), 256, 0, stream>>>(xb, w1, offsets, counts, perm_tok, act);
  phase2_kernel<<<dim3(32, NE), 256, 0, stream>>>(act, w2, offsets, counts, perm_tok, perm_wt, out);
}

// Round 3
// 555.444 us; speedup vs baseline: 1.2562x; 1.0183x over previous
//
#include <hip/hip_runtime.h>
#include <hip/hip_bf16.h>

#define HIDDEN 2048
#define INNER  1024
#define NE     64
#define TOPK   8
#define NTOK   512

typedef float f32x4 __attribute__((ext_vector_type(4)));
typedef short bf16x8 __attribute__((ext_vector_type(8)));

static __device__ __forceinline__ unsigned short b16(float f) {
  return __builtin_bit_cast(unsigned short, __float2bfloat16(f));
}
static __device__ __forceinline__ unsigned int pk2(float lo, float hi) {
  return (unsigned)b16(lo) | ((unsigned)b16(hi) << 16);
}

// ---------------- x -> bf16 ----------------
__global__ void xconv_kernel(const float* __restrict__ x, unsigned short* __restrict__ xb) {
  int i = blockIdx.x * 256 + threadIdx.x;
  float4 v = ((const float4*)x)[i];
  ushort4 o;
  o.x = b16(v.x); o.y = b16(v.y); o.z = b16(v.z); o.w = b16(v.w);
  ((ushort4*)xb)[i] = o;
}

// ---------------- gating: 4 waves per token (K-split), wave0 does softmax+topk ----------------
__global__ __launch_bounds__(256) void gating_kernel(const float* __restrict__ x, const float* __restrict__ gw,
                                                     const float* __restrict__ gb, int* __restrict__ counts,
                                                     int* __restrict__ topk_e, float* __restrict__ topk_w) {
  int t = blockIdx.x;
  int lane = threadIdx.x & 63, w = threadIdx.x >> 6;
  __shared__ float sP[4][NE];
  const float4* xr = (const float4*)(x + (size_t)t * HIDDEN + w * 512);
  const float4* wr = (const float4*)(gw + (size_t)lane * HIDDEN + w * 512);
  float acc = 0.f;
  #pragma unroll 8
  for (int k = 0; k < 128; ++k) {
    float4 a = xr[k], b = wr[k];
    acc += a.x * b.x + a.y * b.y + a.z * b.z + a.w * b.w;
  }
  sP[w][lane] = acc;
  __syncthreads();
  if (w == 0) {
    float logit = gb[lane] + sP[0][lane] + sP[1][lane] + sP[2][lane] + sP[3][lane];
    float m = logit;
    #pragma unroll
    for (int off = 32; off; off >>= 1) m = fmaxf(m, __shfl_xor(m, off));
    float p = __expf(logit - m);
    float s = p;
    #pragma unroll
    for (int off = 32; off; off >>= 1) s += __shfl_xor(s, off);
    p /= s;
    float myp = p;
    float selw[TOPK]; int sele[TOPK];
    #pragma unroll
    for (int k = 0; k < TOPK; ++k) {
      float v = myp; int ei = lane;
      #pragma unroll
      for (int off = 32; off; off >>= 1) {
        float v2 = __shfl_xor(v, off); int e2 = __shfl_xor(ei, off);
        if (v2 > v || (v2 == v && e2 < ei)) { v = v2; ei = e2; }
      }
      selw[k] = v; sele[k] = ei;
      if (lane == ei) myp = -1.0f;
    }
    float ss = 0.f;
    #pragma unroll
    for (int k = 0; k < TOPK; ++k) ss += selw[k];
    if (lane < TOPK) {
      topk_e[t * TOPK + lane] = sele[lane];
      topk_w[t * TOPK + lane] = selw[lane] / ss;
      atomicAdd(&counts[sele[lane]], 1);
    }
  }
}

// ---------------- parallel exclusive scan over 64 counts ----------------
__global__ void scan_kernel(const int* __restrict__ counts, int* __restrict__ offsets,
                            int* __restrict__ cursors) {
  int lane = threadIdx.x;
  int c = counts[lane];
  int s = c;
  #pragma unroll
  for (int off = 1; off < 64; off <<= 1) {
    int o = __shfl_up(s, off);
    if (lane >= off) s += o;
  }
  offsets[lane] = s - c;
  cursors[lane] = 0;
}

// ---------------- scatter assignments into expert-sorted order ----------------
__global__ void scatter_kernel(const int* __restrict__ topk_e, const float* __restrict__ topk_w,
                               const int* __restrict__ offsets, int* __restrict__ cursors,
                               int* __restrict__ perm_tok, float* __restrict__ perm_wt) {
  int i = blockIdx.x * 256 + threadIdx.x;
  int e = topk_e[i];
  int p = atomicAdd(&cursors[e], 1);
  int pos = offsets[e] + p;
  perm_tok[pos] = i >> 3;
  perm_wt[pos] = topk_w[i];
}

// ---------------- phase 1: h = x @ w1[e]^T, act = gelu(gate)*up ----------------
// tile 128(M tokens) x 64(N inner) x {gate,up}; 8 waves: mat=wave>>2, wm=(wave&3)*32
// grid (16 inner chunks, 64 experts), 512 threads
__global__ __launch_bounds__(512, 4) void phase1_kernel(
    const unsigned short* __restrict__ xb, const float* __restrict__ w1,
    const int* __restrict__ offsets, const int* __restrict__ counts,
    const int* __restrict__ perm_tok, unsigned short* __restrict__ act) {
  const int e = blockIdx.y, c = blockIdx.x;
  const int n_e = counts[e];
  if (n_e == 0) return;
  const int off = offsets[e];
  const int tid = threadIdx.x;
  const int lane = tid & 63, wave = tid >> 6;
  const int mat = wave >> 2;          // 0 = gate, 1 = up
  const int wm  = (wave & 3) * 32;

  // B staging: combined 128 rows (0-63 gate, 64-127 up), 16 f32 per thread
  const int sr = tid >> 2, sq = tid & 3;
  const float* srow = w1 + (size_t)e * (2 * INNER) * HIDDEN
      + (size_t)(sr < 64 ? (c * 64 + sr) : (INNER + c * 64 + (sr - 64))) * HIDDEN;
  // A staging: rows tid>>3 and tid>>3 + 64, one 16B chunk each
  const int ar0 = tid >> 3, ar1 = (tid >> 3) + 64;
  const int as = tid & 7;
  const int sxa = as ^ (ar0 & 7);     // same for ar1 (ar1&7 == ar0&7)

  __shared__ uint4 sA[128 * 8];
  __shared__ uint4 sB[128 * 8];
  __shared__ float sU[128][68];       // up-acc exchange, padded
  __shared__ int   stok[128];

  for (int m0 = 0; m0 < n_e; m0 += 128) {
    __syncthreads();
    if (tid < 128) {
      int idx = m0 + tid;
      stok[tid] = perm_tok[off + (idx < n_e ? idx : n_e - 1)];
    }
    __syncthreads();

    // prologue: load k0 = 0 into regs
    uint4 va0, va1; f32x4 vb0, vb1, vb2, vb3;
    va0 = *((const uint4*)(xb + (size_t)stok[ar0] * HIDDEN) + as);
    va1 = *((const uint4*)(xb + (size_t)stok[ar1] * HIDDEN) + as);
    {
      const f32x4* bp = (const f32x4*)srow + sq * 4;
      vb0 = __builtin_nontemporal_load(bp + 0);
      vb1 = __builtin_nontemporal_load(bp + 1);
      vb2 = __builtin_nontemporal_load(bp + 2);
      vb3 = __builtin_nontemporal_load(bp + 3);
    }

    f32x4 acc[2][4];
    #pragma unroll
    for (int i = 0; i < 2; ++i)
      #pragma unroll
      for (int j = 0; j < 4; ++j) acc[i][j] = (f32x4)0.f;

    for (int k0 = 0; k0 < HIDDEN; k0 += 64) {
      // staged regs -> LDS
      sA[ar0 * 8 + sxa] = va0;
      sA[ar1 * 8 + sxa] = va1;
      {
        uint4 w0 = { pk2(vb0.x, vb0.y), pk2(vb0.z, vb0.w), pk2(vb1.x, vb1.y), pk2(vb1.z, vb1.w) };
        uint4 w1q= { pk2(vb2.x, vb2.y), pk2(vb2.z, vb2.w), pk2(vb3.x, vb3.y), pk2(vb3.z, vb3.w) };
        sB[sr * 8 + ((2 * sq)     ^ (sr & 7))] = w0;
        sB[sr * 8 + ((2 * sq + 1) ^ (sr & 7))] = w1q;
      }
      __syncthreads();
      // issue next k-step loads; MFMA phase below covers their latency
      int k1 = k0 + 64;
      if (k1 < HIDDEN) {
        va0 = *((const uint4*)(xb + (size_t)stok[ar0] * HIDDEN + k1) + as);
        va1 = *((const uint4*)(xb + (size_t)stok[ar1] * HIDDEN + k1) + as);
        const f32x4* bp = (const f32x4*)(srow + k1) + sq * 4;
        vb0 = __builtin_nontemporal_load(bp + 0);
        vb1 = __builtin_nontemporal_load(bp + 1);
        vb2 = __builtin_nontemporal_load(bp + 2);
        vb3 = __builtin_nontemporal_load(bp + 3);
      }
      #pragma unroll
      for (int ks = 0; ks < 2; ++ks) {
        const int u = ks * 4 + (lane >> 4);
        bf16x8 af[2], bfr[4];
        #pragma unroll
        for (int mi = 0; mi < 2; ++mi) {
          int r = wm + mi * 16 + (lane & 15);
          af[mi] = __builtin_bit_cast(bf16x8, sA[r * 8 + (u ^ (r & 7))]);
        }
        #pragma unroll
        for (int ni = 0; ni < 4; ++ni) {
          int r = mat * 64 + ni * 16 + (lane & 15);
          bfr[ni] = __builtin_bit_cast(bf16x8, sB[r * 8 + (u ^ (r & 7))]);
        }
        #pragma unroll
        for (int mi = 0; mi < 2; ++mi)
          #pragma unroll
          for (int ni = 0; ni < 4; ++ni)
            acc[mi][ni] = __builtin_amdgcn_mfma_f32_16x16x32_bf16(af[mi], bfr[ni], acc[mi][ni], 0, 0, 0);
      }
      __syncthreads();
    }

    // epilogue: up waves publish, gate waves combine
    if (mat == 1) {
      #pragma unroll
      for (int mi = 0; mi < 2; ++mi)
        #pragma unroll
        for (int ni = 0; ni < 4; ++ni)
          #pragma unroll
          for (int r4 = 0; r4 < 4; ++r4)
            sU[wm + mi * 16 + (lane >> 4) * 4 + r4][ni * 16 + (lane & 15)] = acc[mi][ni][r4];
    }
    __syncthreads();
    if (mat == 0) {
      #pragma unroll
      for (int mi = 0; mi < 2; ++mi)
        #pragma unroll
        for (int r4 = 0; r4 < 4; ++r4) {
          int mrow = wm + mi * 16 + (lane >> 4) * 4 + r4;
          int m = m0 + mrow;
          if (m < n_e) {
            unsigned short* arow = act + (size_t)(off + m) * INNER + c * 64;
            #pragma unroll
            for (int ni = 0; ni < 4; ++ni) {
              int col = ni * 16 + (lane & 15);
              float g = acc[mi][ni][r4];
              float uu = sU[mrow][col];
              float ge = g / (1.0f + __expf(-1.5957691216057308f * (g + 0.044715f * g * g * g)));
              arow[col] = b16(ge * uu);
            }
          }
        }
    }
  }
}

// ---------------- phase 2: y = act @ w2[e]^T, out[tok] += wt * y ----------------
// tile 128(M) x 128(N out cols); 8 waves: wm=(wave&3)*32, wn=(wave>>2)*64
// grid (16 out chunks, 64 experts), 512 threads
__global__ __launch_bounds__(512, 4) void phase2_kernel(
    const unsigned short* __restrict__ act, const float* __restrict__ w2,
    const int* __restrict__ offsets, const int* __restrict__ counts,
    const int* __restrict__ perm_tok, const float* __restrict__ perm_wt,
    float* __restrict__ out) {
  const int e = blockIdx.y, c = blockIdx.x;
  const int n_e = counts[e];
  if (n_e == 0) return;
  const int off = offsets[e];
  const int tid = threadIdx.x;
  const int lane = tid & 63, wave = tid >> 6;
  const int wm = (wave & 3) * 32;
  const int wn = (wave >> 2) * 64;

  const int sr = tid >> 2, sq = tid & 3;
  const float* srow = w2 + ((size_t)e * HIDDEN + c * 128 + sr) * INNER;
  const int ar0 = tid >> 3, ar1 = (tid >> 3) + 64;
  const int as = tid & 7;
  const int sxa = as ^ (ar0 & 7);

  __shared__ uint4 sA[128 * 8];
  __shared__ uint4 sB[128 * 8];
  __shared__ int   stok[128];
  __shared__ float swt[128];

  for (int m0 = 0; m0 < n_e; m0 += 128) {
    __syncthreads();
    if (tid < 128) {
      int idx = m0 + tid;
      int cl = idx < n_e ? idx : n_e - 1;
      stok[tid] = perm_tok[off + cl];
      swt[tid] = (idx < n_e) ? perm_wt[off + cl] : 0.f;
    }
    __syncthreads();

    const unsigned short* a0 = act + (size_t)(off + (m0 + ar0 < n_e ? m0 + ar0 : n_e - 1)) * INNER;
    const unsigned short* a1 = act + (size_t)(off + (m0 + ar1 < n_e ? m0 + ar1 : n_e - 1)) * INNER;

    uint4 va0, va1; f32x4 vb0, vb1, vb2, vb3;
    va0 = *((const uint4*)a0 + as);
    va1 = *((const uint4*)a1 + as);
    {
      const f32x4* bp = (const f32x4*)srow + sq * 4;
      vb0 = __builtin_nontemporal_load(bp + 0);
      vb1 = __builtin_nontemporal_load(bp + 1);
      vb2 = __builtin_nontemporal_load(bp + 2);
      vb3 = __builtin_nontemporal_load(bp + 3);
    }

    f32x4 acc[2][4];
    #pragma unroll
    for (int i = 0; i < 2; ++i)
      #pragma unroll
      for (int j = 0; j < 4; ++j) acc[i][j] = (f32x4)0.f;

    for (int k0 = 0; k0 < INNER; k0 += 64) {
      sA[ar0 * 8 + sxa] = va0;
      sA[ar1 * 8 + sxa] = va1;
      {
        uint4 w0 = { pk2(vb0.x, vb0.y), pk2(vb0.z, vb0.w), pk2(vb1.x, vb1.y), pk2(vb1.z, vb1.w) };
        uint4 w1q= { pk2(vb2.x, vb2.y), pk2(vb2.z, vb2.w), pk2(vb3.x, vb3.y), pk2(vb3.z, vb3.w) };
        sB[sr * 8 + ((2 * sq)     ^ (sr & 7))] = w0;
        sB[sr * 8 + ((2 * sq + 1) ^ (sr & 7))] = w1q;
      }
      __syncthreads();
      int k1 = k0 + 64;
      if (k1 < INNER) {
        va0 = *((const uint4*)(a0 + k1) + as);
        va1 = *((const uint4*)(a1 + k1) + as);
        const f32x4* bp = (const f32x4*)(srow + k1) + sq * 4;
        vb0 = __builtin_nontemporal_load(bp + 0);
        vb1 = __builtin_nontemporal_load(bp + 1);
        vb2 = __builtin_nontemporal_load(bp + 2);
        vb3 = __builtin_nontemporal_load(bp + 3);
      }
      #pragma unroll
      for (int ks = 0; ks < 2; ++ks) {
        const int u = ks * 4 + (lane >> 4);
        bf16x8 af[2], bfr[4];
        #pragma unroll
        for (int mi = 0; mi < 2; ++mi) {
          int r = wm + mi * 16 + (lane & 15);
          af[mi] = __builtin_bit_cast(bf16x8, sA[r * 8 + (u ^ (r & 7))]);
        }
        #pragma unroll
        for (int ni = 0; ni < 4; ++ni) {
          int r = wn + ni * 16 + (lane & 15);
          bfr[ni] = __builtin_bit_cast(bf16x8, sB[r * 8 + (u ^ (r & 7))]);
        }
        #pragma unroll
        for (int mi = 0; mi < 2; ++mi)
          #pragma unroll
          for (int ni = 0; ni < 4; ++ni)
            acc[mi][ni] = __builtin_amdgcn_mfma_f32_16x16x32_bf16(af[mi], bfr[ni], acc[mi][ni], 0, 0, 0);
      }
      __syncthreads();
    }

    // epilogue: out[tok, c*128 + wn + col] += wt * y
    #pragma unroll
    for (int mi = 0; mi < 2; ++mi)
      #pragma unroll
      for (int r4 = 0; r4 < 4; ++r4) {
        int mrow = wm + mi * 16 + (lane >> 4) * 4 + r4;
        int m = m0 + mrow;
        if (m < n_e) {
          int tok = stok[mrow];
          float wt = swt[mrow];
          float* orow = out + (size_t)tok * HIDDEN + c * 128 + wn;
          #pragma unroll
          for (int ni = 0; ni < 4; ++ni)
            atomicAdd(&orow[ni * 16 + (lane & 15)], wt * acc[mi][ni][r4]);
        }
      }
  }
}

extern "C" void kernel_launch(void* const* d_in, const int* in_sizes, int n_in,
                              void* d_out, int out_size, void* d_ws, size_t ws_size,
                              hipStream_t stream) {
  const float* x  = (const float*)d_in[0];
  const float* gw = (const float*)d_in[1];
  const float* gb = (const float*)d_in[2];
  const float* w1 = (const float*)d_in[3];
  const float* w2 = (const float*)d_in[4];
  float* out = (float*)d_out;

  char* ws = (char*)d_ws;
  int*   counts   = (int*)(ws + 0x000);
  int*   offsets  = (int*)(ws + 0x100);
  int*   cursors  = (int*)(ws + 0x200);
  int*   topk_e   = (int*)(ws + 0x1000);
  float* topk_w   = (float*)(ws + 0x5000);
  int*   perm_tok = (int*)(ws + 0x9000);
  float* perm_wt  = (float*)(ws + 0xD000);
  unsigned short* xb  = (unsigned short*)(ws + 0x11000);   // 512*2048 bf16 = 2 MB
  unsigned short* act = (unsigned short*)(ws + 0x220000);  // 4096*1024 bf16 = 8 MB

  hipMemsetAsync(ws, 0, 0x400, stream);
  hipMemsetAsync(d_out, 0, (size_t)out_size * sizeof(float), stream);

  xconv_kernel<<<(NTOK * HIDDEN / 4) / 256, 256, 0, stream>>>(x, xb);
  gating_kernel<<<NTOK, 256, 0, stream>>>(x, gw, gb, counts, topk_e, topk_w);
  scan_kernel<<<1, 64, 0, stream>>>(counts, offsets, cursors);
  scatter_kernel<<<(NTOK * TOPK) / 256, 256, 0, stream>>>(topk_e, topk_w, offsets, cursors,
                                                          perm_tok, perm_wt);
  phase1_kernel<<<dim3(16, NE), 512, 0, stream>>>(xb, w1, offsets, counts, perm_tok, act);
  phase2_kernel<<<dim3(16, NE), 512, 0, stream>>>(act, w2, offsets, counts, perm_tok, perm_wt, out);
}